// Round 4
// baseline (489.132 us; speedup 1.0000x reference)
//
#include <hip/hip_runtime.h>

#define HW_ 4096
#define KSEL 409               // int(0.1 * 4096)
#define T0BITS 0x3FC00000u     // bit pattern of 1.5f; pre-filter |x| > 1.5

__device__ __forceinline__ unsigned absbits(unsigned u) { return u & 0x7FFFFFFFu; }

// Wave-autonomous suffix-scan over a wave-private LDS histogram. No barriers.
// Finds bin b = largest bin with count(>b) < kneed <= count(>=b).
// Returns bin, rem = kneed - count(>b), ceq = count(==b), broadcast to all lanes.
template<int NBINS>
__device__ __forceinline__ void wave_scan(const unsigned* hist, unsigned kneed, int lane,
                                          unsigned& bin, unsigned& rem, unsigned& ceq) {
  constexpr int C = NBINS / 64;          // bins per lane (32 or 16)
  unsigned hs[C];
  #pragma unroll
  for (int q = 0; q < C / 4; ++q) {
    uint4 u = *(const uint4*)&hist[C * lane + 4 * q];   // ds_read_b128
    hs[4*q+0] = u.x; hs[4*q+1] = u.y; hs[4*q+2] = u.z; hs[4*q+3] = u.w;
  }
  unsigned val = 0;
  #pragma unroll
  for (int j = 0; j < C; ++j) val += hs[j];
  // inclusive suffix scan across lanes (higher lane = higher bins)
  unsigned inc = val;
  #pragma unroll
  for (int off = 1; off < 64; off <<= 1) {
    unsigned u = __shfl_down(inc, off);
    if (lane + off < 64) inc += u;
  }
  // crossing lane = highest lane with inc >= kneed (inc is non-increasing in lane)
  unsigned long long m = __ballot(inc >= kneed);
  int cl = 63 - __builtin_clzll(m);
  // every lane computes its own candidate; only the crossing lane's is kept
  unsigned bin_c = 0, rem_c = 0, ceq_c = 0, cum = inc - val;
  bool found = false;
  #pragma unroll
  for (int j = C - 1; j >= 0; --j) {
    unsigned h = hs[j];
    if (!found && cum + h >= kneed) {
      bin_c = C * lane + j; rem_c = kneed - cum; ceq_c = h; found = true;
    }
    if (!found) cum += h;
  }
  bin = __shfl(bin_c, cl);
  rem = __shfl(rem_c, cl);
  ceq = __shfl(ceq_c, cl);
}

extern "C" __global__ void __launch_bounds__(256, 4)
topk_wave(const float* __restrict__ x, float* __restrict__ out) {
  __shared__ unsigned histall[4][2048];   // one private histogram per wave
  const int lane = threadIdx.x & 63;
  const int wv = threadIdx.x >> 6;
  unsigned* hist = histall[wv];
  const size_t row = (size_t)blockIdx.x * 4 + wv;   // one wave per row
  const uint4* xr = (const uint4*)(x + row * HW_);
  uint4* orow = (uint4*)(out + row * HW_);

  // Whole row in this wave's registers: 64 floats/lane as 16x uint4 (coalesced).
  uint4 v[16];
  #pragma unroll
  for (int j = 0; j < 16; ++j) v[j] = xr[lane + 64 * j];

  // Zero pass-1 histogram (2048 words, 32/lane, b128 stores).
  #pragma unroll
  for (int q = 0; q < 8; ++q)
    *(uint4*)&hist[32 * lane + 4 * q] = make_uint4(0, 0, 0, 0);

  // Pre-filter: count |x| > 1.5 (E~547 >= 409 with prob 1-1e-9; exact fallback else).
  unsigned cnt = 0;
  #pragma unroll
  for (int j = 0; j < 16; ++j) {
    cnt += (absbits(v[j].x) > T0BITS);
    cnt += (absbits(v[j].y) > T0BITS);
    cnt += (absbits(v[j].z) > T0BITS);
    cnt += (absbits(v[j].w) > T0BITS);
  }
  unsigned red = cnt;
  #pragma unroll
  for (int off = 1; off < 64; off <<= 1) red += __shfl_down(red, off);  // lane0 total ok
  const unsigned c0 = __shfl(red, 0);
  const bool filt = (c0 >= KSEL);

  // ---- pass 1: bits [30:20], 2048 bins, wave-private atomics ----
  #pragma unroll
  for (int j = 0; j < 16; ++j) {
    unsigned a;
    a = absbits(v[j].x); if (!filt || a > T0BITS) atomicAdd(&hist[a >> 20], 1u);
    a = absbits(v[j].y); if (!filt || a > T0BITS) atomicAdd(&hist[a >> 20], 1u);
    a = absbits(v[j].z); if (!filt || a > T0BITS) atomicAdd(&hist[a >> 20], 1u);
    a = absbits(v[j].w); if (!filt || a > T0BITS) atomicAdd(&hist[a >> 20], 1u);
  }
  unsigned b1, k2, ceq1;
  wave_scan<2048>(hist, KSEL, lane, b1, k2, ceq1);

  // ---- pass 2: bits [19:10] among (ab>>20)==b1, 1024 bins ----
  #pragma unroll
  for (int q = 0; q < 4; ++q)
    *(uint4*)&hist[16 * lane + 4 * q] = make_uint4(0, 0, 0, 0);
  #pragma unroll
  for (int j = 0; j < 16; ++j) {
    unsigned a;
    a = absbits(v[j].x); if ((a >> 20) == b1) atomicAdd(&hist[(a >> 10) & 0x3FFu], 1u);
    a = absbits(v[j].y); if ((a >> 20) == b1) atomicAdd(&hist[(a >> 10) & 0x3FFu], 1u);
    a = absbits(v[j].z); if ((a >> 20) == b1) atomicAdd(&hist[(a >> 10) & 0x3FFu], 1u);
    a = absbits(v[j].w); if ((a >> 20) == b1) atomicAdd(&hist[(a >> 10) & 0x3FFu], 1u);
  }
  unsigned b2, k3, ceq2;
  wave_scan<1024>(hist, k2, lane, b2, k3, ceq2);
  const unsigned P21 = (b1 << 10) | b2;   // bits [30:10] of threshold

  // ---- pass 3: bits [9:0] among (ab>>10)==P21, 1024 bins ----
  #pragma unroll
  for (int q = 0; q < 4; ++q)
    *(uint4*)&hist[16 * lane + 4 * q] = make_uint4(0, 0, 0, 0);
  #pragma unroll
  for (int j = 0; j < 16; ++j) {
    unsigned a;
    a = absbits(v[j].x); if ((a >> 10) == P21) atomicAdd(&hist[a & 0x3FFu], 1u);
    a = absbits(v[j].y); if ((a >> 10) == P21) atomicAdd(&hist[a & 0x3FFu], 1u);
    a = absbits(v[j].z); if ((a >> 10) == P21) atomicAdd(&hist[a & 0x3FFu], 1u);
    a = absbits(v[j].w); if ((a >> 10) == P21) atomicAdd(&hist[a & 0x3FFu], 1u);
  }
  unsigned b3, rem, ceq;
  wave_scan<1024>(hist, k3, lane, b3, rem, ceq);
  const unsigned T = (P21 << 10) | b3;    // exact k-th largest |x| bit pattern

  // ---- keep mask: one bit per element (64 elems/lane -> 64-bit mask) ----
  unsigned long long keep = 0;
  #pragma unroll
  for (int j = 0; j < 16; ++j) {
    if (absbits(v[j].x) > T) keep |= (1ull << (4*j+0));
    if (absbits(v[j].y) > T) keep |= (1ull << (4*j+1));
    if (absbits(v[j].z) > T) keep |= (1ull << (4*j+2));
    if (absbits(v[j].w) > T) keep |= (1ull << (4*j+3));
  }

  if (rem == ceq) {                       // common: keep every element equal to T
    #pragma unroll
    for (int j = 0; j < 16; ++j) {
      if (absbits(v[j].x) == T) keep |= (1ull << (4*j+0));
      if (absbits(v[j].y) == T) keep |= (1ull << (4*j+1));
      if (absbits(v[j].z) == T) keep |= (1ull << (4*j+2));
      if (absbits(v[j].w) == T) keep |= (1ull << (4*j+3));
    }
  } else {
    // Rare exact-bitwise-tie path: keep first `rem` equals in element-index
    // order. Element index = 256j + 4*lane + e -> lexicographic (j, lane, e).
    unsigned base = 0;
    #pragma unroll
    for (int j = 0; j < 16; ++j) {
      unsigned eqm = 0;
      if (absbits(v[j].x) == T) eqm |= 1u;
      if (absbits(v[j].y) == T) eqm |= 2u;
      if (absbits(v[j].z) == T) eqm |= 4u;
      if (absbits(v[j].w) == T) eqm |= 8u;
      unsigned c = __popc(eqm);
      unsigned inc2 = c;                  // inclusive prefix over lanes
      #pragma unroll
      for (int off = 1; off < 64; off <<= 1) {
        unsigned u = __shfl_up(inc2, off);
        if (lane >= off) inc2 += u;
      }
      unsigned r = base + inc2 - c;       // rank of my first equal in this j-group
      unsigned tot = __shfl(inc2, 63);
      #pragma unroll
      for (int e = 0; e < 4; ++e) {
        if ((eqm >> e) & 1u) { if (r < rem) keep |= (1ull << (4*j+e)); ++r; }
      }
      base += tot;
    }
  }

  // ---- coalesced b128 store ----
  #pragma unroll
  for (int j = 0; j < 16; ++j) {
    uint4 o;
    o.x = ((keep >> (4*j+0)) & 1ull) ? v[j].x : 0u;
    o.y = ((keep >> (4*j+1)) & 1ull) ? v[j].y : 0u;
    o.z = ((keep >> (4*j+2)) & 1ull) ? v[j].z : 0u;
    o.w = ((keep >> (4*j+3)) & 1ull) ? v[j].w : 0u;
    orow[lane + 64 * j] = o;
  }
}

extern "C" void kernel_launch(void* const* d_in, const int* in_sizes, int n_in,
                              void* d_out, int out_size, void* d_ws, size_t ws_size,
                              hipStream_t stream) {
  const float* x = (const float*)d_in[0];
  float* out = (float*)d_out;
  const int rows = in_sizes[0] / HW_;     // 64*256 = 16384 rows of 4096
  topk_wave<<<dim3(rows / 4), dim3(256), 0, stream>>>(x, out);
}